// Round 6
// baseline (73.610 us; speedup 1.0000x reference)
//
#include <hip/hip_runtime.h>
#include <hip/hip_bf16.h>

// Problem constants: B=32, Q_LOG=Q_PHYS=256, E=4096.
#define NB   32
#define NQ   256
#define NE   4096
#define MROWS (NB * NQ)   // 8192 flattened rows of P / M

typedef __attribute__((ext_vector_type(8))) short short8;  // 8 bf16 = 4 VGPRs
typedef __attribute__((ext_vector_type(4))) float f32x4;

#define MFMA(a, b, c) __builtin_amdgcn_mfma_f32_16x16x32_bf16((a), (b), (c), 0, 0, 0)

// Static scratch.
__device__ ushort g_Mbf[MROWS * NQ];     // M = P @ Dsw in bf16, row-major      (4.2 MB)
__device__ float  g_Ct[NB * NQ * NQ];    // C[b] col-major: [b][j][i]           (8.4 MB)
__device__ float  g_edge_val[NE];
__device__ int    g_arrive = 0;          // monotonic arrival counter (mod-512)

// Convert 8 fp32 -> short8 of bf16 (RNE; compiler lowers to v_cvt_pk_bf16_f32).
__device__ __forceinline__ short8 cvt8(float4 u0, float4 u1) {
    short8 s;
    s[0] = (short)__bfloat16_as_ushort(__float2bfloat16(u0.x));
    s[1] = (short)__bfloat16_as_ushort(__float2bfloat16(u0.y));
    s[2] = (short)__bfloat16_as_ushort(__float2bfloat16(u0.z));
    s[3] = (short)__bfloat16_as_ushort(__float2bfloat16(u0.w));
    s[4] = (short)__bfloat16_as_ushort(__float2bfloat16(u1.x));
    s[5] = (short)__bfloat16_as_ushort(__float2bfloat16(u1.y));
    s[6] = (short)__bfloat16_as_ushort(__float2bfloat16(u1.z));
    s[7] = (short)__bfloat16_as_ushort(__float2bfloat16(u1.w));
    return s;
}

__device__ __forceinline__ ushort f2bf(float f) {
    return __bfloat16_as_ushort(__float2bfloat16(f));
}

// ---------------------------------------------------------------------------
// K1: Mbf(8192x256) = P @ Dsw, Dsw = 3*max(d_hw-1,0).
// 64x64 tile, 4 waves (2x2 of 32x32), K=256. B-operand (Dsw^T tile) staged in
// LDS with transform; A-operand (P fp32) loaded + converted inline.
// ---------------------------------------------------------------------------
__global__ __launch_bounds__(256) void gemm1_kernel(const float* __restrict__ P,
                                                    const float* __restrict__ d_hw) {
    __shared__ ushort Ds[64][264];   // Ds[c][k] = bf16(3*relu(d_hw[k][colBase+c]-1))
                                     // row stride 528B -> b128 frag reads 2-way (free)

    const int tid = threadIdx.x;
    const int colBase = blockIdx.x * 64;
    const int rowBase = blockIdx.y * 64;

    // Stage Dsw^T tile: 256 k-rows x 64 cols. 16 passes, float4 per thread.
    {
        const int c4 = (tid & 15) * 4;
        const int kr = tid >> 4;
#pragma unroll
        for (int p = 0; p < 16; ++p) {
            const int k = kr + p * 16;
            float4 v = *(const float4*)&d_hw[k * NQ + colBase + c4];
            Ds[c4 + 0][k] = f2bf(v.x > 1.f ? 3.f * (v.x - 1.f) : 0.f);
            Ds[c4 + 1][k] = f2bf(v.y > 1.f ? 3.f * (v.y - 1.f) : 0.f);
            Ds[c4 + 2][k] = f2bf(v.z > 1.f ? 3.f * (v.z - 1.f) : 0.f);
            Ds[c4 + 3][k] = f2bf(v.w > 1.f ? 3.f * (v.w - 1.f) : 0.f);
        }
    }
    __syncthreads();

    const int wave = tid >> 6, lane = tid & 63;
    const int l15 = lane & 15, koff = (lane >> 4) * 8;
    const int rBase = rowBase + (wave >> 1) * 32;
    const int cLoc  = (wave & 1) * 32 + l15;      // LDS col for b0; +16 for b1

    const float* A0 = P + (rBase + l15) * NQ + koff;
    const float* A1 = A0 + 16 * NQ;

    f32x4 acc00 = {0,0,0,0}, acc01 = {0,0,0,0}, acc10 = {0,0,0,0}, acc11 = {0,0,0,0};
#pragma unroll
    for (int k0 = 0; k0 < NQ; k0 += 32) {
        short8 a0 = cvt8(*(const float4*)(A0 + k0), *(const float4*)(A0 + k0 + 4));
        short8 a1 = cvt8(*(const float4*)(A1 + k0), *(const float4*)(A1 + k0 + 4));
        short8 b0 = *(const short8*)&Ds[cLoc][koff + k0];
        short8 b1 = *(const short8*)&Ds[cLoc + 16][koff + k0];
        acc00 = MFMA(a0, b0, acc00);
        acc01 = MFMA(a0, b1, acc01);
        acc10 = MFMA(a1, b0, acc10);
        acc11 = MFMA(a1, b1, acc11);
    }

    // C/D layout: col = lane&15, row = (lane>>4)*4 + reg.
    const int orow = (lane >> 4) * 4;
    const int cBase = colBase + (wave & 1) * 32 + l15;
#pragma unroll
    for (int i = 0; i < 4; ++i) {
        g_Mbf[(rBase + orow + i) * NQ + cBase]           = f2bf(acc00[i]);
        g_Mbf[(rBase + orow + i) * NQ + cBase + 16]      = f2bf(acc01[i]);
        g_Mbf[(rBase + 16 + orow + i) * NQ + cBase]      = f2bf(acc10[i]);
        g_Mbf[(rBase + 16 + orow + i) * NQ + cBase + 16] = f2bf(acc11[i]);
    }
}

// ---------------------------------------------------------------------------
// K2: C[b] = M[b] @ P[b]^T (NT). A = Mbf (bf16, direct), B = P fp32 inline-
// converted. Store col-major [b][j][i] -> contiguous f32x4 per accumulator.
// ---------------------------------------------------------------------------
__global__ __launch_bounds__(256) void gemm2_kernel(const float* __restrict__ P) {
    const int b = blockIdx.z;
    const int tid = threadIdx.x;
    const int wave = tid >> 6, lane = tid & 63;
    const int l15 = lane & 15, koff = (lane >> 4) * 8;
    const int iBase = blockIdx.y * 64 + (wave >> 1) * 32;
    const int jBase = blockIdx.x * 64 + (wave & 1) * 32;

    const ushort* A0 = g_Mbf + (b * NQ + iBase + l15) * NQ + koff;
    const ushort* A1 = A0 + 16 * NQ;
    const float*  B0 = P + (b * NQ + jBase + l15) * NQ + koff;
    const float*  B1 = B0 + 16 * NQ;

    f32x4 acc00 = {0,0,0,0}, acc01 = {0,0,0,0}, acc10 = {0,0,0,0}, acc11 = {0,0,0,0};
#pragma unroll
    for (int k0 = 0; k0 < NQ; k0 += 32) {
        short8 a0 = *(const short8*)(A0 + k0);
        short8 a1 = *(const short8*)(A1 + k0);
        short8 b0 = cvt8(*(const float4*)(B0 + k0), *(const float4*)(B0 + k0 + 4));
        short8 b1 = cvt8(*(const float4*)(B1 + k0), *(const float4*)(B1 + k0 + 4));
        acc00 = MFMA(a0, b0, acc00);
        acc01 = MFMA(a0, b1, acc01);
        acc10 = MFMA(a1, b0, acc10);
        acc11 = MFMA(a1, b1, acc11);
    }

    const int orow = (lane >> 4) * 4;
    float* Cb = g_Ct + b * (NQ * NQ);
    *(f32x4*)&Cb[(jBase + l15) * NQ + iBase + orow]           = acc00;
    *(f32x4*)&Cb[(jBase + 16 + l15) * NQ + iBase + orow]      = acc01;
    *(f32x4*)&Cb[(jBase + l15) * NQ + iBase + 16 + orow]      = acc10;
    *(f32x4*)&Cb[(jBase + 16 + l15) * NQ + iBase + 16 + orow] = acc11;
}

// ---------------------------------------------------------------------------
// K3: fused gather + finalize. 512 blocks x 256 thr = 131072 threads =
// exactly one C-scalar per thread (8 edges/block, 32 batches/edge).
// Last-arriving block (monotonic counter mod 512) does the final reduction.
// ---------------------------------------------------------------------------
__global__ __launch_bounds__(256) void gather_final_kernel(const int* __restrict__ edge_i,
                                                           const int* __restrict__ edge_j,
                                                           const float* __restrict__ edge_w,
                                                           float* __restrict__ out) {
    const int tid = threadIdx.x;
    const int e = blockIdx.x * 8 + (tid >> 5);
    const int b = tid & 31;

    const int i = edge_i[e];
    const int j = edge_j[e];
    float v = g_Ct[b * (NQ * NQ) + j * NQ + i];

    // reduce over b within each 32-lane half-wave group
#pragma unroll
    for (int off = 16; off > 0; off >>= 1) v += __shfl_down(v, off, 32);
    if (b == 0) g_edge_val[e] = edge_w[e] * (v * (1.0f / NB));

    // arrival counter; last block finalizes
    __threadfence();
    __syncthreads();
    __shared__ int s_last;
    if (tid == 0) {
        int old = atomicAdd(&g_arrive, 1);
        s_last = ((old & 511) == 511);
    }
    __syncthreads();
    if (!s_last) return;
    __threadfence();

    float num = 0.f, den = 0.f;
    for (int e2 = tid; e2 < NE; e2 += 256) {
        num += g_edge_val[e2];
        den += edge_w[e2];
    }
#pragma unroll
    for (int off = 32; off > 0; off >>= 1) {
        num += __shfl_down(num, off);
        den += __shfl_down(den, off);
    }
    __shared__ float pn[4], pd[4];
    const int wid = tid >> 6;
    if ((tid & 63) == 0) { pn[wid] = num; pd[wid] = den; }
    __syncthreads();
    if (tid == 0) {
        float n = pn[0] + pn[1] + pn[2] + pn[3];
        float d = pd[0] + pd[1] + pd[2] + pd[3];
        d = d > 1e-8f ? d : 1e-8f;
        out[0] = n / d;
    }
}

extern "C" void kernel_launch(void* const* d_in, const int* in_sizes, int n_in,
                              void* d_out, int out_size, void* d_ws, size_t ws_size,
                              hipStream_t stream) {
    const float* P      = (const float*)d_in[0];
    const float* d_hw   = (const float*)d_in[1];
    const int*   edge_i = (const int*)d_in[2];
    const int*   edge_j = (const int*)d_in[3];
    const float* edge_w = (const float*)d_in[4];
    float* out = (float*)d_out;

    gemm1_kernel<<<dim3(4, 128), 256, 0, stream>>>(P, d_hw);
    gemm2_kernel<<<dim3(4, 4, NB), 256, 0, stream>>>(P);
    gather_final_kernel<<<512, 256, 0, stream>>>(edge_i, edge_j, edge_w, out);
}

// Round 7
// 42.643 us; speedup vs baseline: 1.7262x; 1.7262x over previous
//
#include <hip/hip_runtime.h>
#include <hip/hip_bf16.h>

// Problem constants: B=32, Q_LOG=Q_PHYS=256, E=4096.
#define NB   32
#define NQ   256
#define NE   4096
#define MROWS (NB * NQ)   // 8192 flattened rows of P / M

typedef __attribute__((ext_vector_type(8))) short short8;  // 8 bf16 = 4 VGPRs
typedef __attribute__((ext_vector_type(4))) float f32x4;

#define MFMA(a, b, c) __builtin_amdgcn_mfma_f32_16x16x32_bf16((a), (b), (c), 0, 0, 0)

// Static scratch.
__device__ ushort g_Mbf[MROWS * NQ];     // M = P @ Dsw in bf16, row-major      (4.2 MB)
__device__ float  g_Ct[NB * NQ * NQ];    // C[b] col-major: [b][j][i]           (8.4 MB)
__device__ float  g_edge_val[NE];

// Convert 8 fp32 -> short8 of bf16 (RNE; compiler lowers to v_cvt_pk_bf16_f32).
__device__ __forceinline__ short8 cvt8(float4 u0, float4 u1) {
    short8 s;
    s[0] = (short)__bfloat16_as_ushort(__float2bfloat16(u0.x));
    s[1] = (short)__bfloat16_as_ushort(__float2bfloat16(u0.y));
    s[2] = (short)__bfloat16_as_ushort(__float2bfloat16(u0.z));
    s[3] = (short)__bfloat16_as_ushort(__float2bfloat16(u0.w));
    s[4] = (short)__bfloat16_as_ushort(__float2bfloat16(u1.x));
    s[5] = (short)__bfloat16_as_ushort(__float2bfloat16(u1.y));
    s[6] = (short)__bfloat16_as_ushort(__float2bfloat16(u1.z));
    s[7] = (short)__bfloat16_as_ushort(__float2bfloat16(u1.w));
    return s;
}

__device__ __forceinline__ ushort f2bf(float f) {
    return __bfloat16_as_ushort(__float2bfloat16(f));
}

// ---------------------------------------------------------------------------
// K1: Mbf(8192x256) = P @ Dsw, Dsw = 3*max(d_hw-1,0).
// 64x64 tile, 4 waves (2x2 of 32x32), K=256. B-operand (Dsw^T tile) staged in
// LDS with transform; A-operand (P fp32) loaded + converted inline.
// ---------------------------------------------------------------------------
__global__ __launch_bounds__(256) void gemm1_kernel(const float* __restrict__ P,
                                                    const float* __restrict__ d_hw) {
    __shared__ ushort Ds[64][264];   // Ds[c][k]; row stride 528B -> b128 reads 2-way (free)

    const int tid = threadIdx.x;
    const int colBase = blockIdx.x * 64;
    const int rowBase = blockIdx.y * 64;

    // Stage Dsw^T tile: 256 k-rows x 64 cols. 16 passes, float4 per thread.
    {
        const int c4 = (tid & 15) * 4;
        const int kr = tid >> 4;
#pragma unroll
        for (int p = 0; p < 16; ++p) {
            const int k = kr + p * 16;
            float4 v = *(const float4*)&d_hw[k * NQ + colBase + c4];
            Ds[c4 + 0][k] = f2bf(v.x > 1.f ? 3.f * (v.x - 1.f) : 0.f);
            Ds[c4 + 1][k] = f2bf(v.y > 1.f ? 3.f * (v.y - 1.f) : 0.f);
            Ds[c4 + 2][k] = f2bf(v.z > 1.f ? 3.f * (v.z - 1.f) : 0.f);
            Ds[c4 + 3][k] = f2bf(v.w > 1.f ? 3.f * (v.w - 1.f) : 0.f);
        }
    }
    __syncthreads();

    const int wave = tid >> 6, lane = tid & 63;
    const int l15 = lane & 15, koff = (lane >> 4) * 8;
    const int rBase = rowBase + (wave >> 1) * 32;
    const int cLoc  = (wave & 1) * 32 + l15;

    const float* A0 = P + (rBase + l15) * NQ + koff;
    const float* A1 = A0 + 16 * NQ;

    f32x4 acc00 = {0,0,0,0}, acc01 = {0,0,0,0}, acc10 = {0,0,0,0}, acc11 = {0,0,0,0};
#pragma unroll
    for (int k0 = 0; k0 < NQ; k0 += 32) {
        short8 a0 = cvt8(*(const float4*)(A0 + k0), *(const float4*)(A0 + k0 + 4));
        short8 a1 = cvt8(*(const float4*)(A1 + k0), *(const float4*)(A1 + k0 + 4));
        short8 b0 = *(const short8*)&Ds[cLoc][koff + k0];
        short8 b1 = *(const short8*)&Ds[cLoc + 16][koff + k0];
        acc00 = MFMA(a0, b0, acc00);
        acc01 = MFMA(a0, b1, acc01);
        acc10 = MFMA(a1, b0, acc10);
        acc11 = MFMA(a1, b1, acc11);
    }

    // C/D layout: col = lane&15, row = (lane>>4)*4 + reg.
    const int orow = (lane >> 4) * 4;
    const int cBase = colBase + (wave & 1) * 32 + l15;
#pragma unroll
    for (int i = 0; i < 4; ++i) {
        g_Mbf[(rBase + orow + i) * NQ + cBase]           = f2bf(acc00[i]);
        g_Mbf[(rBase + orow + i) * NQ + cBase + 16]      = f2bf(acc01[i]);
        g_Mbf[(rBase + 16 + orow + i) * NQ + cBase]      = f2bf(acc10[i]);
        g_Mbf[(rBase + 16 + orow + i) * NQ + cBase + 16] = f2bf(acc11[i]);
    }
}

// ---------------------------------------------------------------------------
// K2: C[b] = M[b] @ P[b]^T (NT). A = Mbf (bf16, direct), B = P fp32 inline-
// converted. Store col-major [b][j][i] -> contiguous f32x4 per accumulator.
// ---------------------------------------------------------------------------
__global__ __launch_bounds__(256) void gemm2_kernel(const float* __restrict__ P) {
    const int b = blockIdx.z;
    const int tid = threadIdx.x;
    const int wave = tid >> 6, lane = tid & 63;
    const int l15 = lane & 15, koff = (lane >> 4) * 8;
    const int iBase = blockIdx.y * 64 + (wave >> 1) * 32;
    const int jBase = blockIdx.x * 64 + (wave & 1) * 32;

    const ushort* A0 = g_Mbf + (b * NQ + iBase + l15) * NQ + koff;
    const ushort* A1 = A0 + 16 * NQ;
    const float*  B0 = P + (b * NQ + jBase + l15) * NQ + koff;
    const float*  B1 = B0 + 16 * NQ;

    f32x4 acc00 = {0,0,0,0}, acc01 = {0,0,0,0}, acc10 = {0,0,0,0}, acc11 = {0,0,0,0};
#pragma unroll
    for (int k0 = 0; k0 < NQ; k0 += 32) {
        short8 a0 = *(const short8*)(A0 + k0);
        short8 a1 = *(const short8*)(A1 + k0);
        short8 b0 = cvt8(*(const float4*)(B0 + k0), *(const float4*)(B0 + k0 + 4));
        short8 b1 = cvt8(*(const float4*)(B1 + k0), *(const float4*)(B1 + k0 + 4));
        acc00 = MFMA(a0, b0, acc00);
        acc01 = MFMA(a0, b1, acc01);
        acc10 = MFMA(a1, b0, acc10);
        acc11 = MFMA(a1, b1, acc11);
    }

    const int orow = (lane >> 4) * 4;
    float* Cb = g_Ct + b * (NQ * NQ);
    *(f32x4*)&Cb[(jBase + l15) * NQ + iBase + orow]           = acc00;
    *(f32x4*)&Cb[(jBase + 16 + l15) * NQ + iBase + orow]      = acc01;
    *(f32x4*)&Cb[(jBase + l15) * NQ + iBase + 16 + orow]      = acc10;
    *(f32x4*)&Cb[(jBase + 16 + l15) * NQ + iBase + 16 + orow] = acc11;
}

// ---------------------------------------------------------------------------
// K3: edge gather. 512 blocks x 256 thr: thread (e, b) reads one C scalar;
// half-wave shfl reduce over b. NO fences, NO atomics.
// ---------------------------------------------------------------------------
__global__ __launch_bounds__(256) void edge_gather_kernel(const int* __restrict__ edge_i,
                                                          const int* __restrict__ edge_j,
                                                          const float* __restrict__ edge_w) {
    const int tid = threadIdx.x;
    const int e = blockIdx.x * 8 + (tid >> 5);
    const int b = tid & 31;

    const int i = edge_i[e];
    const int j = edge_j[e];
    float v = g_Ct[b * (NQ * NQ) + j * NQ + i];

#pragma unroll
    for (int off = 16; off > 0; off >>= 1) v += __shfl_down(v, off, 32);
    if (b == 0) g_edge_val[e] = edge_w[e] * (v * (1.0f / NB));
}

// ---------------------------------------------------------------------------
// K4: single-block deterministic final reduction.
// ---------------------------------------------------------------------------
__global__ __launch_bounds__(256) void finalize_kernel(const float* __restrict__ edge_w,
                                                       float* __restrict__ out) {
    const int tid = threadIdx.x;
    float num = 0.f, den = 0.f;
    for (int e = tid; e < NE; e += 256) {
        num += g_edge_val[e];
        den += edge_w[e];
    }
#pragma unroll
    for (int off = 32; off > 0; off >>= 1) {
        num += __shfl_down(num, off);
        den += __shfl_down(den, off);
    }
    __shared__ float pn[4], pd[4];
    const int wid = tid >> 6;
    if ((tid & 63) == 0) { pn[wid] = num; pd[wid] = den; }
    __syncthreads();
    if (tid == 0) {
        float n = pn[0] + pn[1] + pn[2] + pn[3];
        float d = pd[0] + pd[1] + pd[2] + pd[3];
        d = d > 1e-8f ? d : 1e-8f;
        out[0] = n / d;
    }
}

extern "C" void kernel_launch(void* const* d_in, const int* in_sizes, int n_in,
                              void* d_out, int out_size, void* d_ws, size_t ws_size,
                              hipStream_t stream) {
    const float* P      = (const float*)d_in[0];
    const float* d_hw   = (const float*)d_in[1];
    const int*   edge_i = (const int*)d_in[2];
    const int*   edge_j = (const int*)d_in[3];
    const float* edge_w = (const float*)d_in[4];
    float* out = (float*)d_out;

    gemm1_kernel<<<dim3(4, 128), 256, 0, stream>>>(P, d_hw);
    gemm2_kernel<<<dim3(4, 4, NB), 256, 0, stream>>>(P);
    edge_gather_kernel<<<512, 256, 0, stream>>>(edge_i, edge_j, edge_w);
    finalize_kernel<<<1, 256, 0, stream>>>(edge_w, out);
}